// Round 17
// baseline (235.290 us; speedup 1.0000x reference)
//
#include <hip/hip_runtime.h>

#define NGRAPH 1000
#define P      100
#define EPG    1200
#define INF    16
#define HID    64
#define NOUT   5

#define ASTR   88    // unified row: cols 0..63 Y, 64..71 T1a, 72..79 T2, 80..87 T1b
#define T2OFF  72
#define SLOTA  64
#define SLOTB  80
#define NPAD   112   // 7 MFMA row-tiles x 16; rows 100..111 = pad/metadata

// All LDS activations are PACKED: one 32-bit word = bf16(hi)<<16 | bf16(x-hi).
// Producers (gather writes, epilogue, feat load) pack once; consumers unpack
// cheaply (gather: 3 ops/val under LDS latency; MFMA A-frag: 2 shift/or per
// val vs r16's 6-op bsplit x4-redundant). W is pre-split+transposed into d_ws
// by wprep (constant across blocks -> zero per-block conversion):
//   Wt layout per layer: [col][RK], RK = 3F+8, rows 3F..3F+7 zeroed (q3 quad).
//   shorts: L1hi@0(3584) L1lo@3584 | L2hi@7168(12800) L2lo@19968
//           L3hi@32768 L3lo@45568  | total 58368 shorts = 116,736 B in d_ws.
//
// LDS: A 112*88*4 = 39,424 + csr_src(u8) 1,200 = 40,624 -> 4 blocks/CU.
// Metadata in A's pad rows: deg@8800, cur@8900, csr_off@9000(101),
// dinv@9104(100), psum@9204(320). Guarded row<P epilogue stores keep it alive.
//
// HARD RULES (r6..r16): acc arrays compile-time unrolled only; gather loop
// body simple (r11); csr in LDS (r13); conflicts secondary (r13/r14).

typedef short short8 __attribute__((ext_vector_type(8)));
typedef int   int4v  __attribute__((ext_vector_type(4)));
typedef float f32x4  __attribute__((ext_vector_type(4)));
union HL { int4v i; short8 s; };

// unpack packed word -> fp32 (hi + lo)
__device__ __forceinline__ float funp(float f) {
    unsigned p = __float_as_uint(f);
    return __uint_as_float(p & 0xffff0000u) + __uint_as_float(p << 16);
}
// pack fp32 -> packed word
__device__ __forceinline__ float fpk(float x) {
    unsigned u = __float_as_uint(x);
    unsigned hb = u & 0xffff0000u;
    float lo = x - __uint_as_float(hb);
    return __uint_as_float(hb | (__float_as_uint(lo) >> 16));
}

// ---- W split/transpose pre-kernel (runs every launch; ~3 us) ----
__global__ __launch_bounds__(256) void wprep(
    const float* __restrict__ W1, const float* __restrict__ W2,
    const float* __restrict__ W3, short* __restrict__ wt)
{
    const int i0 = blockIdx.x * blockDim.x + threadIdx.x;
    const int stride = gridDim.x * blockDim.x;
    for (int e = i0; e < HID * 56; e += stride) {           // layer 1, RK=56
        int c = e / 56, r = e % 56;
        float v = (r < 48) ? W1[r * HID + c] : 0.f;
        unsigned u = __float_as_uint(v);
        unsigned hb = u & 0xffff0000u;
        float lo = v - __uint_as_float(hb);
        wt[e]        = (short)(hb >> 16);
        wt[3584 + e] = (short)(__float_as_uint(lo) >> 16);
    }
    for (int e = i0; e < HID * 200; e += stride) {          // layers 2+3, RK=200
        int c = e / 200, r = e % 200;
        float v2 = (r < 192) ? W2[r * HID + c] : 0.f;
        float v3 = (r < 192) ? W3[r * HID + c] : 0.f;
        unsigned u2 = __float_as_uint(v2);
        unsigned h2 = u2 & 0xffff0000u;
        float l2 = v2 - __uint_as_float(h2);
        wt[7168 + e]  = (short)(h2 >> 16);
        wt[19968 + e] = (short)(__float_as_uint(l2) >> 16);
        unsigned u3 = __float_as_uint(v3);
        unsigned h3 = u3 & 0xffff0000u;
        float l3 = v3 - __uint_as_float(h3);
        wt[32768 + e] = (short)(h3 >> 16);
        wt[45568 + e] = (short)(__float_as_uint(l3) >> 16);
    }
}

// ---- gather phase (r15 dataflow, packed load/store) ----
__device__ __forceinline__ void prop_x1(
    float* __restrict__ A, int soff, int dslot,
    const unsigned char* __restrict__ csr_src,
    const int* __restrict__ csr_off,
    const float* __restrict__ dinv, int tid)
{
    const int q4 = (tid & 1) * 4;
    const int n  = tid >> 1;
    if (n < P) {
        const int kb = csr_off[n], ke = csr_off[n + 1];
        float ax = 0.f, ay = 0.f, az = 0.f, aw = 0.f;
        for (int k = kb; k < ke; k++) {
            int s = csr_src[k];
            const float4 x = *(const float4*)&A[s * ASTR + soff + q4];
            ax += funp(x.x); ay += funp(x.y); az += funp(x.z); aw += funp(x.w);
        }
        float dn = dinv[n];
        float m = -dn * dn;
        float4 o;
        o.x = fpk(m * ax); o.y = fpk(m * ay); o.z = fpk(m * az); o.w = fpk(m * aw);
        *(float4*)&A[n * ASTR + dslot + q4] = o;
    }
}

__device__ __forceinline__ void prop_dual(
    float* __restrict__ A, int t1c, int t1n, int ycur, int ynext, bool pre,
    const unsigned char* __restrict__ csr_src,
    const int* __restrict__ csr_off,
    const float* __restrict__ dinv, int tid)
{
    const int q4 = (tid & 1) * 4;
    const int n  = tid >> 1;
    if (n < P) {
        const int kb = csr_off[n], ke = csr_off[n + 1];
        float4 a2 = make_float4(0.f, 0.f, 0.f, 0.f);
        float4 a1 = make_float4(0.f, 0.f, 0.f, 0.f);
        if (pre) {
            for (int k = kb; k < ke; k++) {
                int s = csr_src[k];
                const float* rp = &A[s * ASTR + q4];
                const float4 x2 = *(const float4*)&rp[t1c];
                const float4 x1 = *(const float4*)&rp[ynext];
                a2.x += funp(x2.x); a2.y += funp(x2.y);
                a2.z += funp(x2.z); a2.w += funp(x2.w);
                a1.x += funp(x1.x); a1.y += funp(x1.y);
                a1.z += funp(x1.z); a1.w += funp(x1.w);
            }
        } else {
            for (int k = kb; k < ke; k++) {
                int s = csr_src[k];
                const float4 x2 = *(const float4*)&A[s * ASTR + t1c + q4];
                a2.x += funp(x2.x); a2.y += funp(x2.y);
                a2.z += funp(x2.z); a2.w += funp(x2.w);
            }
        }
        float dn = dinv[n];
        float d2 = dn * dn;
        const float4 y0 = *(const float4*)&A[n * ASTR + ycur + q4];
        float m2 = -2.f * d2;
        float4 o2;
        o2.x = fpk(m2 * a2.x - funp(y0.x)); o2.y = fpk(m2 * a2.y - funp(y0.y));
        o2.z = fpk(m2 * a2.z - funp(y0.z)); o2.w = fpk(m2 * a2.w - funp(y0.w));
        *(float4*)&A[n * ASTR + T2OFF + q4] = o2;
        if (pre) {
            float m1 = -d2;
            float4 o1;
            o1.x = fpk(m1 * a1.x); o1.y = fpk(m1 * a1.y);
            o1.z = fpk(m1 * a1.z); o1.w = fpk(m1 * a1.w);
            *(float4*)&A[n * ASTR + t1n + q4] = o1;
        }
    }
}

// ---- one ChebConv layer: gather + MFMA matmul (packed operands) ----
template <int F, int FINAL>
__device__ __forceinline__ void cheb_layer(
    float* __restrict__ A,
    const unsigned char* __restrict__ csr_src,
    const int* __restrict__ csr_off,
    const float* __restrict__ dinv,
    const short* __restrict__ whi, const short* __restrict__ wlo,
    const float* __restrict__ bias, int tid)
{
    const int RK   = 3 * F + 8;
    const int lane = tid & 63;
    const int wv   = tid >> 6;          // wave = col-tile (cols wv*16..+15)
    const int n16  = lane & 15;
    const int q    = lane >> 4;         // K-quad: 0=Y(cb) 1=T1 2=T2 3=zero
    const int ncol = (wv << 4) + n16;

    f32x4 acc[7];
#pragma unroll
    for (int t = 0; t < 7; t++) { acc[t][0]=0.f; acc[t][1]=0.f; acc[t][2]=0.f; acc[t][3]=0.f; }

    prop_x1(A, 0, SLOTA, csr_src, csr_off, dinv, tid);
    __syncthreads();

    int t1c = SLOTA, t1n = SLOTB;
    for (int cb = 0; cb < F; cb += 8) {
        const bool pre = (cb + 8 < F);
        prop_dual(A, t1c, t1n, cb, cb + 8, pre, csr_src, csr_off, dinv, tid);
        __syncthreads();

        // B fragment: precomputed split W (global, L1/L2-resident)
        const int wr = (q == 0) ? cb : (q == 1) ? (F + cb)
                     : (q == 2) ? (2 * F + cb) : (3 * F);   // 3F.. = zero block
        const short8 bhi = *(const short8*)&whi[ncol * RK + wr];
        const short8 blo = *(const short8*)&wlo[ncol * RK + wr];

        const int aoff = (q == 0) ? cb : (q == 1) ? t1c
                       : (q == 2) ? T2OFF : cb;
#pragma unroll
        for (int t = 0; t < 7; t++) {
            const int4v p0 = *(const int4v*)&A[(t * 16 + n16) * ASTR + aoff];
            const int4v p1 = *(const int4v*)&A[(t * 16 + n16) * ASTR + aoff + 4];
            HL hi, lo;
            hi.i[0] = (int)((((unsigned)p0[0]) >> 16) | (((unsigned)p0[1]) & 0xffff0000u));
            hi.i[1] = (int)((((unsigned)p0[2]) >> 16) | (((unsigned)p0[3]) & 0xffff0000u));
            hi.i[2] = (int)((((unsigned)p1[0]) >> 16) | (((unsigned)p1[1]) & 0xffff0000u));
            hi.i[3] = (int)((((unsigned)p1[2]) >> 16) | (((unsigned)p1[3]) & 0xffff0000u));
            lo.i[0] = (int)((p0[0] & 0xffff) | (((unsigned)p0[1]) << 16));
            lo.i[1] = (int)((p0[2] & 0xffff) | (((unsigned)p0[3]) << 16));
            lo.i[2] = (int)((p1[0] & 0xffff) | (((unsigned)p1[1]) << 16));
            lo.i[3] = (int)((p1[2] & 0xffff) | (((unsigned)p1[3]) << 16));
            acc[t] = __builtin_amdgcn_mfma_f32_16x16x32_bf16(hi.s, bhi, acc[t], 0, 0, 0);
            acc[t] = __builtin_amdgcn_mfma_f32_16x16x32_bf16(hi.s, blo, acc[t], 0, 0, 0);
            acc[t] = __builtin_amdgcn_mfma_f32_16x16x32_bf16(lo.s, bhi, acc[t], 0, 0, 0);
        }
        __syncthreads();
        int tt = t1c; t1c = t1n; t1n = tt;
    }

    // Epilogue: D col=lane&15, row=(lane>>4)*4+reg (m89). Guard row<P keeps
    // pad-row metadata intact. FINAL=0 stores packed Y; FINAL=1 raw fp32 H.
    const float bcol = bias[ncol];
    const int rbase = q * 4;
#pragma unroll
    for (int t = 0; t < 7; t++) {
#pragma unroll
        for (int r = 0; r < 4; r++) {
            int row = t * 16 + rbase + r;
            if (row < P) {
                float dn = dinv[row];
                float v = acc[t][r];
                float o;
                if (FINAL) o = fmaxf(v * (1.0f / dn) + bcol, 0.f);
                else       o = fpk(fmaxf(v + bcol * dn, 0.f));
                A[row * ASTR + ncol] = o;
            }
        }
    }
    __syncthreads();
}

__global__ __launch_bounds__(256, 4) void gnn_kernel(
    const float* __restrict__ feat,
    const int* __restrict__ src, const int* __restrict__ dst,
    const float* __restrict__ b1, const float* __restrict__ b2,
    const float* __restrict__ b3,
    const float* __restrict__ Wfc, const float* __restrict__ bfc,
    const short* __restrict__ wt,
    float* __restrict__ out)
{
    __shared__ __align__(16) float A[NPAD * ASTR];
    __shared__ unsigned char csr_src[EPG];

    const int g = blockIdx.x;
    const int tid = threadIdx.x;
    const int base = g * P;
    const int* srcg = src + g * EPG;
    const int* dstg = dst + g * EPG;

    int*   deg     = (int*)&A[P * ASTR];          // 8800
    int*   cur     = (int*)&A[P * ASTR + 100];    // 8900
    int*   csr_off = (int*)&A[P * ASTR + 200];    // 9000 (101 ints)
    float* dinv    = &A[P * ASTR + 304];          // 9104 (100 f32)
    float* psum    = &A[P * ASTR + 404];          // 9204 (320 f32)

    // ---- degree count ----
    for (int i = tid; i < P; i += 256) deg[i] = 0;
    __syncthreads();
    for (int e = tid; e < EPG; e += 256) {
        int d = dstg[e] - base;
        atomicAdd(&deg[d], 1);
    }
    __syncthreads();

    // ---- dinv + serial prefix scan ----
    for (int i = tid; i < P; i += 256) {
        int dg = deg[i] > 1 ? deg[i] : 1;
        dinv[i] = rsqrtf((float)dg);
    }
    if (tid == 0) {
        int run = 0;
        csr_off[0] = 0;
        for (int i = 0; i < P; i++) { run += deg[i]; csr_off[i + 1] = run; }
    }
    __syncthreads();

    // ---- feat load prescaled + packed + CSR cursor init ----
    for (int i = tid; i < P * INF / 4; i += 256) {
        int n = i >> 2, fq = (i & 3) * 4;
        float4 v = *(const float4*)&feat[(size_t)base * INF + i * 4];
        float dn = dinv[n];
        float4 o;
        o.x = fpk(v.x * dn); o.y = fpk(v.y * dn);
        o.z = fpk(v.z * dn); o.w = fpk(v.w * dn);
        *(float4*)&A[n * ASTR + fq] = o;
    }
    for (int i = tid; i < P; i += 256) cur[i] = csr_off[i];
    __syncthreads();
    // ---- CSR fill (u8 node ids, LDS) ----
    for (int e = tid; e < EPG; e += 256) {
        int s = srcg[e] - base;
        int d = dstg[e] - base;
        int pos = atomicAdd(&cur[d], 1);
        csr_src[pos] = (unsigned char)s;
    }
    __syncthreads();

    // ---- 3 ChebConv layers ----
    cheb_layer<INF, 0>(A, csr_src, csr_off, dinv, wt,         wt + 3584,  b1, tid);
    cheb_layer<HID, 0>(A, csr_src, csr_off, dinv, wt + 7168,  wt + 19968, b2, tid);
    cheb_layer<HID, 1>(A, csr_src, csr_off, dinv, wt + 32768, wt + 45568, b3, tid);

    // ---- mean pool + FC (H is raw fp32 after FINAL layer) ----
    {
        const int lane = tid & 63, w = tid >> 6;
        float s = 0.f;
        for (int n = w; n < P; n += 4) s += A[n * ASTR + lane];
        psum[w * 64 + lane] = s;
    }
    __syncthreads();
    if (tid < HID) {
        float hg = (psum[tid] + psum[64 + tid] + psum[128 + tid] + psum[192 + tid]) * (1.0f / P);
        psum[256 + tid] = hg;
    }
    __syncthreads();
    if (tid < NOUT) {
        float o = bfc[tid];
        for (int c = 0; c < HID; c++) o += psum[256 + c] * Wfc[c * NOUT + tid];
        out[g * NOUT + tid] = o;
    }
}

extern "C" void kernel_launch(void* const* d_in, const int* in_sizes, int n_in,
                              void* d_out, int out_size, void* d_ws, size_t ws_size,
                              hipStream_t stream)
{
    const float* feat = (const float*)d_in[0];
    const int*   src  = (const int*)d_in[1];
    const int*   dst  = (const int*)d_in[2];
    const float* W1  = (const float*)d_in[5];
    const float* b1  = (const float*)d_in[6];
    const float* W2  = (const float*)d_in[7];
    const float* b2  = (const float*)d_in[8];
    const float* W3  = (const float*)d_in[9];
    const float* b3  = (const float*)d_in[10];
    const float* Wfc = (const float*)d_in[11];
    const float* bfc = (const float*)d_in[12];
    float* out = (float*)d_out;
    short* wt = (short*)d_ws;

    wprep<<<64, 256, 0, stream>>>(W1, W2, W3, wt);
    gnn_kernel<<<NGRAPH, 256, 0, stream>>>(feat, src, dst,
                                           b1, b2, b3, Wfc, bfc, wt, out);
}

// Round 18
// 186.023 us; speedup vs baseline: 1.2648x; 1.2648x over previous
//
#include <hip/hip_runtime.h>

#define NGRAPH 1000
#define P      100
#define EPG    1200
#define INF    16
#define HID    64
#define NOUT   5

#define ASTR   88    // unified row: cols 0..63 Y, 64..71 T1a, 72..79 T2, 80..87 T1b
#define T2OFF  72
#define SLOTA  64
#define SLOTB  80
#define NPAD   112   // 7 MFMA row-tiles x 16; rows 100..111 = pad/metadata

// r18 = r16 (raw-fp32 LDS activations, verified 122 us) + wprep W tables:
//  - W pre-split (bf16 hi/lo) + transposed to [col][RK] in d_ws, RK=3F+8,
//    rows 3F..3F+7 zeroed -> q3 K-quad contributes 0 regardless of A garbage
//    (kills both the per-slice B bsplit AND the qsc masking muls).
//  - activations stay RAW fp32 in LDS: r17 proved packed format taxes the
//    gather's ~12x read amplification (VALUBusy 53->60, dur +35%). REVERTED.
//   wt shorts: L1hi@0(3584) L1lo@3584 | L2hi@7168(12800) L2lo@19968
//              L3hi@32768 L3lo@45568 | total 58368 shorts = 116,736 B.
//
// LDS: A 112*88*4 = 39,424 + csr_src(u8) 1,200 = 40,624 -> 4 blocks/CU.
// Metadata in A's pad rows: deg@8800, cur@8900, csr_off@9000(101),
// dinv@9104(100), psum@9204(320). Guarded row<P epilogue stores keep it alive.
//
// HARD RULES (r6..r17): acc arrays compile-time unrolled only; gather loop
// body simple + raw fp32 (r11/r17); csr in LDS (r13); conflicts secondary.

typedef short short8 __attribute__((ext_vector_type(8)));
typedef float f32x4  __attribute__((ext_vector_type(4)));

__device__ __forceinline__ void bsplit(float x, short& h, short& l) {
    unsigned u = __float_as_uint(x);
    h = (short)(u >> 16);
    float hf = __uint_as_float(u & 0xffff0000u);
    l = (short)(__float_as_uint(x - hf) >> 16);
}

// ---- W split/transpose pre-kernel (runs every launch; ~3 us) ----
__global__ __launch_bounds__(256) void wprep(
    const float* __restrict__ W1, const float* __restrict__ W2,
    const float* __restrict__ W3, short* __restrict__ wt)
{
    const int i0 = blockIdx.x * blockDim.x + threadIdx.x;
    const int stride = gridDim.x * blockDim.x;
    for (int e = i0; e < HID * 56; e += stride) {           // layer 1, RK=56
        int c = e / 56, r = e % 56;
        float v = (r < 48) ? W1[r * HID + c] : 0.f;
        short h, l; bsplit(v, h, l);
        wt[e]        = h;
        wt[3584 + e] = l;
    }
    for (int e = i0; e < HID * 200; e += stride) {          // layers 2+3, RK=200
        int c = e / 200, r = e % 200;
        float v2 = (r < 192) ? W2[r * HID + c] : 0.f;
        float v3 = (r < 192) ? W3[r * HID + c] : 0.f;
        short h, l;
        bsplit(v2, h, l); wt[7168 + e]  = h; wt[19968 + e] = l;
        bsplit(v3, h, l); wt[32768 + e] = h; wt[45568 + e] = l;
    }
}

// ---- gather phase (r15/r16 verbatim: raw fp32, u8 indices) ----
__device__ __forceinline__ void prop_x1(
    float* __restrict__ A, int soff, int dslot,
    const unsigned char* __restrict__ csr_src,
    const int* __restrict__ csr_off,
    const float* __restrict__ dinv, int tid)
{
    const int q4 = (tid & 1) * 4;
    const int n  = tid >> 1;
    if (n < P) {
        const int kb = csr_off[n], ke = csr_off[n + 1];
        float ax = 0.f, ay = 0.f, az = 0.f, aw = 0.f;
        for (int k = kb; k < ke; k++) {
            int s = csr_src[k];
            const float4 x = *(const float4*)&A[s * ASTR + soff + q4];
            ax += x.x; ay += x.y; az += x.z; aw += x.w;
        }
        float dn = dinv[n];
        float m = -dn * dn;
        float4 o; o.x = m * ax; o.y = m * ay; o.z = m * az; o.w = m * aw;
        *(float4*)&A[n * ASTR + dslot + q4] = o;
    }
}

__device__ __forceinline__ void prop_dual(
    float* __restrict__ A, int t1c, int t1n, int ycur, int ynext, bool pre,
    const unsigned char* __restrict__ csr_src,
    const int* __restrict__ csr_off,
    const float* __restrict__ dinv, int tid)
{
    const int q4 = (tid & 1) * 4;
    const int n  = tid >> 1;
    if (n < P) {
        const int kb = csr_off[n], ke = csr_off[n + 1];
        float4 a2 = make_float4(0.f, 0.f, 0.f, 0.f);
        float4 a1 = make_float4(0.f, 0.f, 0.f, 0.f);
        if (pre) {
            for (int k = kb; k < ke; k++) {
                int s = csr_src[k];
                const float* rp = &A[s * ASTR + q4];
                const float4 x2 = *(const float4*)&rp[t1c];
                const float4 x1 = *(const float4*)&rp[ynext];
                a2.x += x2.x; a2.y += x2.y; a2.z += x2.z; a2.w += x2.w;
                a1.x += x1.x; a1.y += x1.y; a1.z += x1.z; a1.w += x1.w;
            }
        } else {
            for (int k = kb; k < ke; k++) {
                int s = csr_src[k];
                const float4 x2 = *(const float4*)&A[s * ASTR + t1c + q4];
                a2.x += x2.x; a2.y += x2.y; a2.z += x2.z; a2.w += x2.w;
            }
        }
        float dn = dinv[n];
        float d2 = dn * dn;
        const float4 y0 = *(const float4*)&A[n * ASTR + ycur + q4];
        float4 o2;
        float m2 = -2.f * d2;
        o2.x = m2 * a2.x - y0.x; o2.y = m2 * a2.y - y0.y;
        o2.z = m2 * a2.z - y0.z; o2.w = m2 * a2.w - y0.w;
        *(float4*)&A[n * ASTR + T2OFF + q4] = o2;
        if (pre) {
            float m1 = -d2;
            float4 o1;
            o1.x = m1 * a1.x; o1.y = m1 * a1.y;
            o1.z = m1 * a1.z; o1.w = m1 * a1.w;
            *(float4*)&A[n * ASTR + t1n + q4] = o1;
        }
    }
}

// ---- one ChebConv layer: gather (raw fp32) + MFMA matmul (split A, table B)
template <int F, int FINAL>
__device__ __forceinline__ void cheb_layer(
    float* __restrict__ A,
    const unsigned char* __restrict__ csr_src,
    const int* __restrict__ csr_off,
    const float* __restrict__ dinv,
    const short* __restrict__ whi, const short* __restrict__ wlo,
    const float* __restrict__ bias, int tid)
{
    const int RK   = 3 * F + 8;
    const int lane = tid & 63;
    const int wv   = tid >> 6;          // wave = col-tile (cols wv*16..+15)
    const int n16  = lane & 15;
    const int q    = lane >> 4;         // K-quad: 0=Y(cb) 1=T1 2=T2 3=zero-B
    const int ncol = (wv << 4) + n16;

    f32x4 acc[7];
#pragma unroll
    for (int t = 0; t < 7; t++) { acc[t][0]=0.f; acc[t][1]=0.f; acc[t][2]=0.f; acc[t][3]=0.f; }

    prop_x1(A, 0, SLOTA, csr_src, csr_off, dinv, tid);
    __syncthreads();

    int t1c = SLOTA, t1n = SLOTB;
    for (int cb = 0; cb < F; cb += 8) {
        const bool pre = (cb + 8 < F);
        prop_dual(A, t1c, t1n, cb, cb + 8, pre, csr_src, csr_off, dinv, tid);
        __syncthreads();

        // B fragment from precomputed tables (q3 -> zeroed rows 3F..3F+7)
        const int wr = (q == 0) ? cb : (q == 1) ? (F + cb)
                     : (q == 2) ? (2 * F + cb) : (3 * F);
        const short8 bhi = *(const short8*)&whi[ncol * RK + wr];
        const short8 blo = *(const short8*)&wlo[ncol * RK + wr];

        // A fragment: q3's aoff points at Y(cb) garbage-free but irrelevant —
        // its B is zero, so no masking needed.
        const int aoff = (q == 0) ? cb : (q == 1) ? t1c
                       : (q == 2) ? T2OFF : cb;
#pragma unroll
        for (int t = 0; t < 7; t++) {
            const float* xp = &A[(t * 16 + n16) * ASTR + aoff];
            const float4 v0 = *(const float4*)xp;
            const float4 v1 = *(const float4*)(xp + 4);
            short8 ahi, alo; short h, l;
            bsplit(v0.x, h, l); ahi[0] = h; alo[0] = l;
            bsplit(v0.y, h, l); ahi[1] = h; alo[1] = l;
            bsplit(v0.z, h, l); ahi[2] = h; alo[2] = l;
            bsplit(v0.w, h, l); ahi[3] = h; alo[3] = l;
            bsplit(v1.x, h, l); ahi[4] = h; alo[4] = l;
            bsplit(v1.y, h, l); ahi[5] = h; alo[5] = l;
            bsplit(v1.z, h, l); ahi[6] = h; alo[6] = l;
            bsplit(v1.w, h, l); ahi[7] = h; alo[7] = l;
            acc[t] = __builtin_amdgcn_mfma_f32_16x16x32_bf16(ahi, bhi, acc[t], 0, 0, 0);
            acc[t] = __builtin_amdgcn_mfma_f32_16x16x32_bf16(ahi, blo, acc[t], 0, 0, 0);
            acc[t] = __builtin_amdgcn_mfma_f32_16x16x32_bf16(alo, bhi, acc[t], 0, 0, 0);
        }
        __syncthreads();
        int tt = t1c; t1c = t1n; t1n = tt;
    }

    // Epilogue: D col=lane&15, row=(lane>>4)*4+reg (m89-verified).
    // Guard row<P keeps pad-row metadata intact.
    const float bcol = bias[ncol];
    const int rbase = q * 4;
#pragma unroll
    for (int t = 0; t < 7; t++) {
#pragma unroll
        for (int r = 0; r < 4; r++) {
            int row = t * 16 + rbase + r;
            if (row < P) {
                float dn = dinv[row];
                float v = acc[t][r];
                float o;
                if (FINAL) o = fmaxf(v * (1.0f / dn) + bcol, 0.f);
                else       o = fmaxf(v + bcol * dn, 0.f);
                A[row * ASTR + ncol] = o;
            }
        }
    }
    __syncthreads();
}

__global__ __launch_bounds__(256, 4) void gnn_kernel(
    const float* __restrict__ feat,
    const int* __restrict__ src, const int* __restrict__ dst,
    const float* __restrict__ b1, const float* __restrict__ b2,
    const float* __restrict__ b3,
    const float* __restrict__ Wfc, const float* __restrict__ bfc,
    const short* __restrict__ wt,
    float* __restrict__ out)
{
    __shared__ __align__(16) float A[NPAD * ASTR];
    __shared__ unsigned char csr_src[EPG];

    const int g = blockIdx.x;
    const int tid = threadIdx.x;
    const int base = g * P;
    const int* srcg = src + g * EPG;
    const int* dstg = dst + g * EPG;

    int*   deg     = (int*)&A[P * ASTR];          // 8800
    int*   cur     = (int*)&A[P * ASTR + 100];    // 8900
    int*   csr_off = (int*)&A[P * ASTR + 200];    // 9000 (101 ints)
    float* dinv    = &A[P * ASTR + 304];          // 9104 (100 f32)
    float* psum    = &A[P * ASTR + 404];          // 9204 (320 f32)

    // ---- degree count ----
    for (int i = tid; i < P; i += 256) deg[i] = 0;
    __syncthreads();
    for (int e = tid; e < EPG; e += 256) {
        int d = dstg[e] - base;
        atomicAdd(&deg[d], 1);
    }
    __syncthreads();

    // ---- dinv + serial prefix scan ----
    for (int i = tid; i < P; i += 256) {
        int dg = deg[i] > 1 ? deg[i] : 1;
        dinv[i] = rsqrtf((float)dg);
    }
    if (tid == 0) {
        int run = 0;
        csr_off[0] = 0;
        for (int i = 0; i < P; i++) { run += deg[i]; csr_off[i + 1] = run; }
    }
    __syncthreads();

    // ---- feat load prescaled (A = dinv*feat) + CSR cursor init ----
    for (int i = tid; i < P * INF / 4; i += 256) {
        int n = i >> 2, fq = (i & 3) * 4;
        float4 v = *(const float4*)&feat[(size_t)base * INF + i * 4];
        float dn = dinv[n];
        v.x *= dn; v.y *= dn; v.z *= dn; v.w *= dn;
        *(float4*)&A[n * ASTR + fq] = v;
    }
    for (int i = tid; i < P; i += 256) cur[i] = csr_off[i];
    __syncthreads();
    // ---- CSR fill (u8 node ids, LDS) ----
    for (int e = tid; e < EPG; e += 256) {
        int s = srcg[e] - base;
        int d = dstg[e] - base;
        int pos = atomicAdd(&cur[d], 1);
        csr_src[pos] = (unsigned char)s;
    }
    __syncthreads();

    // ---- 3 ChebConv layers (prescaled; final layer emits H) ----
    cheb_layer<INF, 0>(A, csr_src, csr_off, dinv, wt,         wt + 3584,  b1, tid);
    cheb_layer<HID, 0>(A, csr_src, csr_off, dinv, wt + 7168,  wt + 19968, b2, tid);
    cheb_layer<HID, 1>(A, csr_src, csr_off, dinv, wt + 32768, wt + 45568, b3, tid);

    // ---- mean pool + FC ----
    {
        const int lane = tid & 63, w = tid >> 6;
        float s = 0.f;
        for (int n = w; n < P; n += 4) s += A[n * ASTR + lane];
        psum[w * 64 + lane] = s;
    }
    __syncthreads();
    if (tid < HID) {
        float hg = (psum[tid] + psum[64 + tid] + psum[128 + tid] + psum[192 + tid]) * (1.0f / P);
        psum[256 + tid] = hg;
    }
    __syncthreads();
    if (tid < NOUT) {
        float o = bfc[tid];
        for (int c = 0; c < HID; c++) o += psum[256 + c] * Wfc[c * NOUT + tid];
        out[g * NOUT + tid] = o;
    }
}

extern "C" void kernel_launch(void* const* d_in, const int* in_sizes, int n_in,
                              void* d_out, int out_size, void* d_ws, size_t ws_size,
                              hipStream_t stream)
{
    const float* feat = (const float*)d_in[0];
    const int*   src  = (const int*)d_in[1];
    const int*   dst  = (const int*)d_in[2];
    const float* W1  = (const float*)d_in[5];
    const float* b1  = (const float*)d_in[6];
    const float* W2  = (const float*)d_in[7];
    const float* b2  = (const float*)d_in[8];
    const float* W3  = (const float*)d_in[9];
    const float* b3  = (const float*)d_in[10];
    const float* Wfc = (const float*)d_in[11];
    const float* bfc = (const float*)d_in[12];
    float* out = (float*)d_out;
    short* wt = (short*)d_ws;

    wprep<<<64, 256, 0, stream>>>(W1, W2, W3, wt);
    gnn_kernel<<<NGRAPH, 256, 0, stream>>>(feat, src, dst,
                                           b1, b2, b3, Wfc, bfc, wt, out);
}